// Round 3
// baseline (597.227 us; speedup 1.0000x reference)
//
#include <hip/hip_runtime.h>
#include <stdint.h>

// BitNet MLP: x[65536,512] --i8gemm--> h --relu^2+SubLN+actquant--> h_q
//             --i8gemm--> out[65536,512].
// GEMM: 256x256 tile, BK=128, 8 waves, 8-phase counted-vmcnt schedule
// (T2 swizzle + T3/T4 counted vmcnt + T5 setprio), mfma_i32_16x16x64_i8.

typedef int v4i __attribute__((ext_vector_type(4)));

#define AS1(p) ((const __attribute__((address_space(1))) void*)(p))
#define AS3(p) ((__attribute__((address_space(3))) void*)(p))

static constexpr size_t OFF_PART = 256;
static constexpr size_t OFF_SX   = 8192;
static constexpr size_t OFF_RSQ  = OFF_SX   + 262144;
static constexpr size_t OFF_S2   = OFF_RSQ  + 262144;
static constexpr size_t OFF_INV2 = OFF_S2   + 262144;
static constexpr size_t OFF_WUQ  = OFF_INV2 + 262144;
static constexpr size_t OFF_WDQ  = OFF_WUQ  + 1048576;
static constexpr size_t OFF_XQ   = OFF_WDQ  + 1048576;
static constexpr size_t OFF_HQ   = OFF_XQ   + 33554432;
static constexpr size_t OFF_SS   = OFF_HQ   + 134217728;
static constexpr size_t OFF_MM   = OFF_SS   + 8388608;

// ---------------- weight |w| partial sums (deterministic, fp64) -------------
__global__ void wabs_partial(const float* __restrict__ w, double* __restrict__ part)
{
    int t = threadIdx.x, bid = blockIdx.x;
    const float4* w4 = (const float4*)w;
    int base = bid * 256 + t;
    double s = 0.0;
    #pragma unroll
    for (int j = 0; j < 4; ++j) {
        float4 v = w4[base + j * 65536];
        s += (double)fabsf(v.x) + (double)fabsf(v.y)
           + (double)fabsf(v.z) + (double)fabsf(v.w);
    }
    #pragma unroll
    for (int off = 32; off > 0; off >>= 1) s += __shfl_down(s, off);
    __shared__ double ps[4];
    int l = t & 63, wv = t >> 6;
    if (l == 0) ps[wv] = s;
    __syncthreads();
    if (t == 0) part[bid] = ((ps[0] + ps[1]) + ps[2]) + ps[3];
}

__global__ void finalize_sums(const double* __restrict__ part, double* __restrict__ sums)
{
    int t = threadIdx.x;
    double a = part[t];
    double b = part[256 + t];
    #pragma unroll
    for (int off = 32; off > 0; off >>= 1) {
        a += __shfl_down(a, off);
        b += __shfl_down(b, off);
    }
    __shared__ double pa[4], pb[4];
    int l = t & 63, wv = t >> 6;
    if (l == 0) { pa[wv] = a; pb[wv] = b; }
    __syncthreads();
    if (t == 0) {
        sums[0] = ((pa[0] + pa[1]) + pa[2]) + pa[3];
        sums[1] = ((pb[0] + pb[1]) + pb[2]) + pb[3];
    }
}

// ---------------- ternary weight quantization -------------------------------
__global__ void wquant(const float* __restrict__ w, const double* __restrict__ sum,
                       signed char* __restrict__ wq)
{
    int i = blockIdx.x * blockDim.x + threadIdx.x;
    if (i >= 262144) return;
    float mean  = (float)(*sum) * (1.0f / 1048576.0f);
    float scale = 1.0f / fmaxf(mean, 1e-5f);
    float4 v = ((const float4*)w)[i];
    int q0 = (int)fminf(fmaxf(rintf(v.x * scale), -1.f), 1.f);
    int q1 = (int)fminf(fmaxf(rintf(v.y * scale), -1.f), 1.f);
    int q2 = (int)fminf(fmaxf(rintf(v.z * scale), -1.f), 1.f);
    int q3 = (int)fminf(fmaxf(rintf(v.w * scale), -1.f), 1.f);
    unsigned pk = (q0 & 255) | ((q1 & 255) << 8) | ((q2 & 255) << 16) | ((q3 & 255) << 24);
    ((unsigned*)wq)[i] = pk;
}

// ---------------- activation quantization of x (per-token, H=512) -----------
__global__ void xquant(const float* __restrict__ x, signed char* __restrict__ xq,
                       float* __restrict__ inv_sx)
{
    int row = blockIdx.x * 4 + (threadIdx.x >> 6);
    int l   = threadIdx.x & 63;
    const float* xr = x + (size_t)row * 512;
    float4 v0 = *(const float4*)(xr + l * 8);
    float4 v1 = *(const float4*)(xr + l * 8 + 4);
    float m = fmaxf(fmaxf(fmaxf(fabsf(v0.x), fabsf(v0.y)), fmaxf(fabsf(v0.z), fabsf(v0.w))),
                    fmaxf(fmaxf(fabsf(v1.x), fabsf(v1.y)), fmaxf(fabsf(v1.z), fabsf(v1.w))));
    #pragma unroll
    for (int off = 1; off < 64; off <<= 1) m = fmaxf(m, __shfl_xor(m, off));
    float mc = fmaxf(m, 1e-5f);
    float s  = 127.0f / mc;
    int q[8];
    q[0] = (int)fminf(fmaxf(rintf(v0.x * s), -128.f), 127.f);
    q[1] = (int)fminf(fmaxf(rintf(v0.y * s), -128.f), 127.f);
    q[2] = (int)fminf(fmaxf(rintf(v0.z * s), -128.f), 127.f);
    q[3] = (int)fminf(fmaxf(rintf(v0.w * s), -128.f), 127.f);
    q[4] = (int)fminf(fmaxf(rintf(v1.x * s), -128.f), 127.f);
    q[5] = (int)fminf(fmaxf(rintf(v1.y * s), -128.f), 127.f);
    q[6] = (int)fminf(fmaxf(rintf(v1.z * s), -128.f), 127.f);
    q[7] = (int)fminf(fmaxf(rintf(v1.w * s), -128.f), 127.f);
    uint2 pk;
    pk.x = (q[0] & 255) | ((q[1] & 255) << 8) | ((q[2] & 255) << 16) | ((q[3] & 255) << 24);
    pk.y = (q[4] & 255) | ((q[5] & 255) << 8) | ((q[6] & 255) << 16) | ((q[7] & 255) << 24);
    *(uint2*)(xq + (size_t)row * 512 + l * 8) = pk;
    if (l == 0) inv_sx[row] = mc * (1.0f / 127.0f);
}

// ---------------- per-row stats reduce --------------------------------------
__global__ void row_reduce(const float* __restrict__ ss_p, const float* __restrict__ mm_p,
                           float* __restrict__ rsq, float* __restrict__ s2,
                           float* __restrict__ inv2)
{
    int row = blockIdx.x * blockDim.x + threadIdx.x;
    float ss = 0.f, mm = 0.f;
    #pragma unroll
    for (int p = 0; p < 32; ++p) {
        ss += ss_p[(size_t)row * 32 + p];
        mm  = fmaxf(mm, mm_p[(size_t)row * 32 + p]);
    }
    float var  = ss * (1.0f / 2048.0f);
    float r    = 1.0f / sqrtf(var + 1e-6f);
    float maxy = fmaxf(r * mm, 1e-5f);
    rsq[row]  = r;
    s2[row]   = 127.0f / maxy;
    inv2[row] = maxy * (1.0f / 127.0f);
}

// ---------------- int8 GEMM, 256x256 tile, 8-phase schedule -----------------
// One phase: {12 ds_read_b128 | 1 region stage (2 gload_lds)} -> barrier ->
// lgkmcnt(0) -> 16 MFMA (setprio) -> barrier.  vmcnt(4) once per K-tile.
// LDS regions (per buf, per op, 256 rows x 128B):
//   A-lo rows [0,64)u[128,192)  (read by phases mh=0: q0,q1)
//   A-hi rows [64,128)u[192,256)       (mh=1: q2,q3)
//   B-even rows with bit5==0           (nh=0: q0,q2)
//   B-odd  rows with bit5==1           (nh=1: q1,q3)
// Issue map (phase of tile kt): q0->A-hi[kt+1], q1->B-odd[kt+1],
//   q2->A-lo[kt+2], q3->B-even[kt+2]  (each target dead at issue time).

#define PHASE(MH, NH, STAGE_STMT, TAIL_STMT)                                   \
  {                                                                            \
    v4i af[8]; v4i bf[4];                                                      \
    _Pragma("unroll")                                                          \
    for (int mm = 0; mm < 4; ++mm) {                                           \
      _Pragma("unroll")                                                        \
      for (int ks = 0; ks < 2; ++ks) {                                         \
        int r  = wr * 128 + ((MH) * 4 + mm) * 16 + lr;                         \
        int eg = (ks * 4 + lg) ^ lx;                                           \
        af[mm * 2 + ks] = *(const v4i*)(Ab + r * 128 + eg * 16);               \
      }                                                                        \
    }                                                                          \
    _Pragma("unroll")                                                          \
    for (int nn = 0; nn < 2; ++nn) {                                           \
      _Pragma("unroll")                                                        \
      for (int ks = 0; ks < 2; ++ks) {                                         \
        int r  = wc * 64 + ((NH) * 2 + nn) * 16 + lr;                          \
        int eg = (ks * 4 + lg) ^ lx;                                           \
        bf[nn * 2 + ks] = *(const v4i*)(Bb + r * 128 + eg * 16);               \
      }                                                                        \
    }                                                                          \
    STAGE_STMT;                                                                \
    __builtin_amdgcn_s_barrier();                                              \
    asm volatile("s_waitcnt lgkmcnt(0)" ::: "memory");                         \
    __builtin_amdgcn_sched_barrier(0);                                         \
    __builtin_amdgcn_s_setprio(1);                                             \
    _Pragma("unroll")                                                          \
    for (int mm = 0; mm < 4; ++mm)                                             \
      _Pragma("unroll")                                                        \
      for (int nn = 0; nn < 2; ++nn)                                           \
        _Pragma("unroll")                                                      \
        for (int ks = 0; ks < 2; ++ks)                                         \
          acc[(MH) * 4 + mm][(NH) * 2 + nn] =                                  \
              __builtin_amdgcn_mfma_i32_16x16x64_i8(                           \
                  af[mm * 2 + ks], bf[nn * 2 + ks],                            \
                  acc[(MH) * 4 + mm][(NH) * 2 + nn], 0, 0, 0);                 \
    __builtin_amdgcn_s_setprio(0);                                             \
    TAIL_STMT;                                                                 \
    __builtin_amdgcn_s_barrier();                                              \
  }

#define KTILE(KT, P)                                                           \
  {                                                                            \
    const char* Ab = &lds[P][0][0];                                            \
    const char* Bb = &lds[P][1][0];                                            \
    const int kt_ = (KT);                                                      \
    PHASE(0, 0, { if (kt_ + 1 < NKT) stageA((P) ^ 1, 1, kt_ + 1); }, {})       \
    PHASE(0, 1, { if (kt_ + 1 < NKT) stageB((P) ^ 1, 1, kt_ + 1); }, {})       \
    PHASE(1, 0, { if (kt_ + 2 < NKT) stageA((P), 0, kt_ + 2); }, {})           \
    PHASE(1, 1, { if (kt_ + 2 < NKT) stageB((P), 0, kt_ + 2); },               \
          {                                                                    \
            if (kt_ < NKT - 1) {                                               \
              if (kt_ + 2 < NKT)                                               \
                asm volatile("s_waitcnt vmcnt(4)" ::: "memory");               \
              else                                                             \
                asm volatile("s_waitcnt vmcnt(0)" ::: "memory");               \
            }                                                                  \
          })                                                                   \
  }

template<int K, int N, int EPI>
__global__ __launch_bounds__(512, 2)
void gemm_i8(const signed char* __restrict__ A,
             const signed char* __restrict__ B,
             const float* __restrict__ rowscale,
             const double* __restrict__ wsum,
             const float* __restrict__ g,
             const float* __restrict__ rsq,
             const float* __restrict__ s2,
             float* __restrict__ st_ss,
             float* __restrict__ st_mm,
             signed char* __restrict__ hq,
             float* __restrict__ out)
{
    constexpr int NKT = K / 128;
    constexpr int NBN = N / 256;
    __shared__ __align__(16) char lds[2][2][32768];   // [buf][A/B][row*128 + g*16]

    // bijective XCD-chunked block swizzle (m204)
    int nwg  = gridDim.x;
    int orig = blockIdx.x;
    int q8 = nwg >> 3, r8 = nwg & 7;
    int xcd = orig & 7, lin = orig >> 3;
    int swz = (xcd < r8 ? xcd * (q8 + 1) : r8 * (q8 + 1) + (xcd - r8) * q8) + lin;
    int mt = swz / NBN, nt = swz - mt * NBN;

    size_t mbase = (size_t)mt * 256;
    int    nbase = nt * 256;

    int t  = threadIdx.x;
    int l  = t & 63;
    int wid = t >> 6;
    int wr = wid >> 2, wc = wid & 3;      // 2 M-waves x 4 N-waves
    int lr = l & 15, lg = l >> 4, lx = l & 7;

    const signed char* Ag = A + mbase * K;
    const signed char* Bg = B + (size_t)nbase * K;

    // stage one 16KB region: LDS linear, global source inverse-swizzled
    // (granule g holds global k-granule g^(row&7)); per-wave dst is
    // uniform-base + lane*16 (verified linear in lane for all region maps).
    auto stageA = [&](int buf, int sel, int ktt) {
        char* d0 = &lds[buf][0][0];
        #pragma unroll
        for (int i = 0; i < 2; ++i) {
            int j = i * 512 + t;
            int rho = j >> 3, gg = j & 7;
            int r = rho + (rho & 64) + sel * 64;
            int kg = gg ^ (r & 7);
            __builtin_amdgcn_global_load_lds(AS1(Ag + (size_t)r * K + ktt * 128 + kg * 16),
                                             AS3(d0 + r * 128 + gg * 16), 16, 0, 0);
        }
    };
    auto stageB = [&](int buf, int sel, int ktt) {
        char* d0 = &lds[buf][1][0];
        #pragma unroll
        for (int i = 0; i < 2; ++i) {
            int j = i * 512 + t;
            int rho = j >> 3, gg = j & 7;
            int r = ((rho & ~31) << 1) + (rho & 31) + sel * 32;
            int kg = gg ^ (r & 7);
            __builtin_amdgcn_global_load_lds(AS1(Bg + (size_t)r * K + ktt * 128 + kg * 16),
                                             AS3(d0 + r * 128 + gg * 16), 16, 0, 0);
        }
    };

    v4i acc[8][4] = {};

    // prologue: tile0 fully + first half of tile1; keep 2 regions in flight
    stageA(0, 0, 0); stageB(0, 0, 0); stageA(0, 1, 0); stageB(0, 1, 0);
    if (NKT > 1) {
        stageA(1, 0, 1); stageB(1, 0, 1);
        asm volatile("s_waitcnt vmcnt(4)" ::: "memory");
    } else {
        asm volatile("s_waitcnt vmcnt(0)" ::: "memory");
    }
    __builtin_amdgcn_s_barrier();

    #pragma unroll 1
    for (int kt2 = 0; kt2 < NKT / 2; ++kt2) {
        int kt = kt2 * 2;
        KTILE(kt, 0)
        KTILE(kt + 1, 1)
    }

    float wmean = fmaxf((float)wsum[0] * (1.0f / 1048576.0f), 1e-5f);
    size_t rowb = mbase + (size_t)wr * 128;   // + m*16 + lg*4 + reg
    int    colb = nbase + wc * 64;            // + n*16 + lr

    if constexpr (EPI == 2) {
        #pragma unroll
        for (int m = 0; m < 8; ++m)
            #pragma unroll
            for (int reg = 0; reg < 4; ++reg) {
                size_t grow = rowb + m * 16 + lg * 4 + reg;
                float f = rowscale[grow] * wmean;
                #pragma unroll
                for (int n = 0; n < 4; ++n)
                    out[grow * N + colb + n * 16 + lr] = (float)acc[m][n][reg] * f;
            }
    } else {
        float gv[4];
        #pragma unroll
        for (int n = 0; n < 4; ++n) gv[n] = g[colb + n * 16 + lr];

        if constexpr (EPI == 0) {
            #pragma unroll
            for (int m = 0; m < 8; ++m)
                #pragma unroll
                for (int reg = 0; reg < 4; ++reg) {
                    size_t grow = rowb + m * 16 + lg * 4 + reg;
                    float f = rowscale[grow] * wmean;
                    float ss = 0.f, mx = 0.f;
                    #pragma unroll
                    for (int n = 0; n < 4; ++n) {
                        float z = (float)acc[m][n][reg] * f;
                        float a = fmaxf(z, 0.f);
                        float h = a * a;
                        ss += h * h;
                        mx  = fmaxf(mx, fabsf(h * gv[n]));
                    }
                    #pragma unroll
                    for (int off = 1; off < 16; off <<= 1) {
                        ss += __shfl_xor(ss, off);
                        mx  = fmaxf(mx, __shfl_xor(mx, off));
                    }
                    if (lr == 0) {
                        st_ss[grow * 32 + nt * 4 + wc] = ss;
                        st_mm[grow * 32 + nt * 4 + wc] = mx;
                    }
                }
        } else {  // EPI == 1
            #pragma unroll
            for (int m = 0; m < 8; ++m)
                #pragma unroll
                for (int reg = 0; reg < 4; ++reg) {
                    size_t grow = rowb + m * 16 + lg * 4 + reg;
                    float f  = rowscale[grow] * wmean;
                    float rq = rsq[grow];
                    float sc = s2[grow];
                    #pragma unroll
                    for (int n = 0; n < 4; ++n) {
                        float z = (float)acc[m][n][reg] * f;
                        float a = fmaxf(z, 0.f);
                        float h = a * a;
                        float y = (h * rq) * gv[n];
                        int qv = (int)fminf(fmaxf(rintf(y * sc), -128.f), 127.f);
                        hq[grow * 2048 + colb + n * 16 + lr] = (signed char)qv;
                    }
                }
        }
    }
}

// ---------------------------------------------------------------------------
extern "C" void kernel_launch(void* const* d_in, const int* in_sizes, int n_in,
                              void* d_out, int out_size, void* d_ws, size_t ws_size,
                              hipStream_t stream)
{
    const float* x  = (const float*)d_in[0];
    const float* wu = (const float*)d_in[1];
    const float* wd = (const float*)d_in[2];
    const float* g  = (const float*)d_in[3];
    float* out = (float*)d_out;
    char*  ws  = (char*)d_ws;

    double* sums     = (double*)ws;
    double* part     = (double*)(ws + OFF_PART);
    float*  inv_sx   = (float*)(ws + OFF_SX);
    float*  rsq      = (float*)(ws + OFF_RSQ);
    float*  s2       = (float*)(ws + OFF_S2);
    float*  inv2     = (float*)(ws + OFF_INV2);
    signed char* wuq = (signed char*)(ws + OFF_WUQ);
    signed char* wdq = (signed char*)(ws + OFF_WDQ);
    signed char* xq  = (signed char*)(ws + OFF_XQ);
    signed char* hq  = (signed char*)(ws + OFF_HQ);
    float*  st_ss    = (float*)(ws + OFF_SS);
    float*  st_mm    = (float*)(ws + OFF_MM);

    wabs_partial<<<256, 256, 0, stream>>>(wu, part);
    wabs_partial<<<256, 256, 0, stream>>>(wd, part + 256);
    finalize_sums<<<1, 256, 0, stream>>>(part, sums);
    wquant<<<1024, 256, 0, stream>>>(wu, sums + 0, wuq);
    wquant<<<1024, 256, 0, stream>>>(wd, sums + 1, wdq);
    xquant<<<16384, 256, 0, stream>>>(x, xq, inv_sx);

    // GEMM1 pass A: stats only
    gemm_i8<512, 2048, 0><<<2048, 512, 0, stream>>>(xq, wuq, inv_sx, sums + 0, g,
                                                    nullptr, nullptr, st_ss, st_mm,
                                                    nullptr, nullptr);
    row_reduce<<<256, 256, 0, stream>>>(st_ss, st_mm, rsq, s2, inv2);
    // GEMM1 pass B: fused relu^2 + SubLN + act_quant -> h_q
    gemm_i8<512, 2048, 1><<<2048, 512, 0, stream>>>(xq, wuq, inv_sx, sums + 0, g,
                                                    rsq, s2, nullptr, nullptr,
                                                    hq, nullptr);
    // GEMM2: h_q @ w_down^T -> out
    gemm_i8<2048, 512, 2><<<512, 512, 0, stream>>>(hq, wdq, inv2, sums + 1,
                                                   nullptr, nullptr, nullptr,
                                                   nullptr, nullptr, nullptr, out);
}